// Round 1
// 259.570 us; speedup vs baseline: 1.0012x; 1.0012x over previous
//
#include <hip/hip_runtime.h>
#include <cmath>

#define NB 2
#define NN 2048
#define ND 128
#define NH 8
#define NL 3
#define NV 32
#define NDH 16
#define LN_EPS 1e-5f
/* ATT_SCALE(0.25) * log2(e), folded into Q at qkv-pack time so the attention
   inner loop is a raw exp2 per score. */
#define QSCALE 0.36067376022224085f

typedef __bf16 bf8_t __attribute__((ext_vector_type(8)));
typedef __bf16 bf4_t __attribute__((ext_vector_type(4)));
typedef float f4x __attribute__((ext_vector_type(4)));
typedef float f16x __attribute__((ext_vector_type(16)));

// ---------------- one prep kernel: weight casts + adjacency/mask bitpack ----
struct CastArgs {
  const float* s[5];
  __bf16* d[5];
  int startblk[5];
};
// blocks [0,592): casts; [592, 592+8192): adj bitpack; [8784, 8800): mask bitpack
__global__ __launch_bounds__(256) void prep_kernel(
    CastArgs a, const float* __restrict__ adj, unsigned long long* __restrict__ abits,
    const int* __restrict__ mask, unsigned long long* __restrict__ mbits) {
  int blk = blockIdx.x;
  int lane = threadIdx.x & 63;
  if (blk < 592) {
    int seg = 0;
#pragma unroll
    for (int i = 1; i < 5; i++) seg += (blk >= a.startblk[i]) ? 1 : 0;
    int i4 = (blk - a.startblk[seg]) * 256 + threadIdx.x;
    float4 v = ((const float4*)a.s[seg])[i4];
    bf4_t p = {(__bf16)v.x, (__bf16)v.y, (__bf16)v.z, (__bf16)v.w};
    ((bf4_t*)a.d[seg])[i4] = p;
  } else if (blk < 592 + 8192) {
    int g = ((blk - 592) * 4 + (threadIdx.x >> 6)) * 4;
    const float* p = adj + (size_t)g * 64 + lane;
    unsigned long long w0 = __ballot(p[0] != 0.0f);
    unsigned long long w1 = __ballot(p[64] != 0.0f);
    unsigned long long w2 = __ballot(p[128] != 0.0f);
    unsigned long long w3 = __ballot(p[192] != 0.0f);
    if (lane == 0) {
      abits[g] = w0; abits[g + 1] = w1; abits[g + 2] = w2; abits[g + 3] = w3;
    }
  } else {
    int g = (blk - 8784) * 4 + (threadIdx.x >> 6);
    int v = mask[g * 64 + lane];
    unsigned long long bal = __ballot(v != 0);
    if (lane == 0) mbits[g] = bal;
  }
}

// ---------------- fused0: embed + in-proj + LN1[0] + qkv[0] ----
// Single-pass block (grid 256): in-proj, then Q,K,V chunks. Weight fragments
// loaded global->register directly (no LDS staging): each wave reads its own
// 16-output-col slice of the 128x128 tile (16 rows x 64B = 16 full cache
// lines per wave-load, L2-resident).
__global__ __launch_bounds__(512) void fused0_kernel(
    const float* __restrict__ atom_embed, const float* __restrict__ cons_embed,
    const int* __restrict__ is_atom, const int* __restrict__ atom_id,
    const __bf16* __restrict__ W1, const float* __restrict__ b1,
    float* __restrict__ Hout,
    const float* __restrict__ lng, const float* __restrict__ lnb,
    const __bf16* __restrict__ W2, const float* __restrict__ b2,
    __bf16* __restrict__ Qb, __bf16* __restrict__ Kb, __bf16* __restrict__ Vt) {
  __shared__ __bf16 Xs[16][136];
  __shared__ float Hs[16][132];
  __shared__ __bf16 X2[16][136];
  int m0 = blockIdx.x * 16;
  int t = threadIdx.x;
  int lane = t & 63, w = t >> 6;
  int l15 = lane & 15, quad = lane >> 4;
  int wrow = w * 16 + l15;

  {
    int r = t >> 5, c = t & 31;
    int row = m0 + r;
    int id = atom_id[row];
    id = id < 0 ? 0 : (id > NV - 1 ? NV - 1 : id);
    const float* src = is_atom[row] ? (atom_embed + (size_t)id * ND) : cons_embed;
    float4 v = *(const float4*)&src[c * 4];
    bf4_t p = {(__bf16)v.x, (__bf16)v.y, (__bf16)v.z, (__bf16)v.w};
    *(bf4_t*)&Xs[r][c * 4] = p;
  }

  bf8_t wcur[4], wnxt[4];
  auto issue = [&](int i, bf8_t* dst) {
    const __bf16* base = (i == 0) ? W1 : (W2 + (size_t)(i - 1) * 128 * 128);
    const __bf16* p = base + (size_t)wrow * 128 + quad * 8;
#pragma unroll
    for (int kk = 0; kk < 4; kk++) dst[kk] = *(const bf8_t*)(p + kk * 32);
  };
  issue(0, wcur);
  __syncthreads();  // Xs ready

  for (int i = 0; i < 4; i++) {
    if (i + 1 < 4) issue(i + 1, wnxt);
    if (i == 0) {
      f4x a1 = {0.f, 0.f, 0.f, 0.f};
#pragma unroll
      for (int kk = 0; kk < 4; kk++) {
        bf8_t a = *(const bf8_t*)&Xs[l15][kk * 32 + quad * 8];
        a1 = __builtin_amdgcn_mfma_f32_16x16x32_bf16(a, wcur[kk], a1, 0, 0, 0);
      }
      int n = wrow;
      float bv = b1[n];
#pragma unroll
      for (int r = 0; r < 4; r++) {
        int m = quad * 4 + r;
        float v = a1[r] + bv;
        Hout[(size_t)(m0 + m) * ND + n] = v;
        Hs[m][n] = v;
      }
      __syncthreads();  // Hs ready
      {
        int r = t >> 5, c = t & 31;
        float4 v = *(const float4*)&Hs[r][c * 4];
        float s1 = v.x + v.y + v.z + v.w;
        float s2 = v.x * v.x + v.y * v.y + v.z * v.z + v.w * v.w;
#pragma unroll
        for (int m = 16; m >= 1; m >>= 1) {
          s1 += __shfl_xor(s1, m, 64);
          s2 += __shfl_xor(s2, m, 64);
        }
        float mean = s1 * (1.0f / ND);
        float var = s2 * (1.0f / ND) - mean * mean;
        float rstd = rsqrtf(var + LN_EPS);
        float4 gg = *(const float4*)&lng[c * 4];
        float4 bb = *(const float4*)&lnb[c * 4];
        bf4_t p;
        p[0] = (__bf16)((v.x - mean) * rstd * gg.x + bb.x);
        p[1] = (__bf16)((v.y - mean) * rstd * gg.y + bb.y);
        p[2] = (__bf16)((v.z - mean) * rstd * gg.z + bb.z);
        p[3] = (__bf16)((v.w - mean) * rstd * gg.w + bb.w);
        *(bf4_t*)&X2[r][c * 4] = p;
      }
      __syncthreads();  // X2 ready
    } else {
      int nc = i - 1;
      f4x a2 = {0.f, 0.f, 0.f, 0.f};
#pragma unroll
      for (int kk = 0; kk < 4; kk++) {
        bf8_t a = *(const bf8_t*)&X2[l15][kk * 32 + quad * 8];
        a2 = __builtin_amdgcn_mfma_f32_16x16x32_bf16(a, wcur[kk], a2, 0, 0, 0);
      }
      int n = nc * 128 + wrow;
      float bv = b2[n];
#pragma unroll
      for (int r = 0; r < 4; r++) {
        int m = m0 + quad * 4 + r;
        float v = a2[r] + bv;
        if (n < ND) Qb[(size_t)m * ND + n] = (__bf16)(v * QSCALE);
        else if (n < 2 * ND) Kb[(size_t)m * ND + n - ND] = (__bf16)v;
        else {
          int c2 = n - 2 * ND, hh = c2 >> 4, d0 = c2 & 15;
          int bb2 = m >> 11, nn = m & 2047;
          Vt[((size_t)((bb2 * NH + hh) * NDH + d0)) * NN + nn] = (__bf16)v;
        }
      }
    }
#pragma unroll
    for (int kk = 0; kk < 4; kk++) wcur[kk] = wnxt[kk];
  }
}

// ---------------- per-layer mega kernel ----------------
// Block = 16 rows, 512 threads, grid 256 (single pass; no duplicated FF for
// the V chunk). T = 12 tiles: out-proj, 4x ff1, 4x ff2, 3x qkv.
// Weight fragments load global->register directly (the old Ws LDS staging was
// a pure round-trip: every element was written and read exactly once). One
// tile of register prefetch hides L2 latency. Barriers only at true
// producer->consumer transitions (~6 instead of 22).
template <int LAST>
__global__ __launch_bounds__(512) void layer_kernel(
    const __bf16* __restrict__ Ob,
    const __bf16* __restrict__ Wout, const float* __restrict__ bout,
    const float* __restrict__ Hin, float* __restrict__ Hout,
    const float* __restrict__ ln2g, const float* __restrict__ ln2b,
    const __bf16* __restrict__ Wff1, const float* __restrict__ bff1,
    const __bf16* __restrict__ Wff2, const float* __restrict__ bff2,
    const float* __restrict__ ln1g, const float* __restrict__ ln1b,
    const __bf16* __restrict__ Wqkv, const float* __restrict__ bqkv,
    __bf16* __restrict__ Qb, __bf16* __restrict__ Kb, __bf16* __restrict__ Vt,
    const int* __restrict__ root_idx, const float* __restrict__ hg,
    const float* __restrict__ hbt, const float* __restrict__ hwp,
    const float* __restrict__ hbp, float* __restrict__ outp) {
  __shared__ __bf16 Xs[16][136];
  __shared__ float Hs[16][132];
  __shared__ __bf16 X2[16][136];
  __shared__ __bf16 Fs[16][520];
  int m0 = blockIdx.x * 16;
  int t = threadIdx.x;
  int lane = t & 63, w = t >> 6;
  int l15 = lane & 15, quad = lane >> 4;
  int wrow = w * 16 + l15;
  const int T = LAST ? 9 : 12;

  {
    int r = t >> 5, c = t & 31;
    *(bf4_t*)&Xs[r][c * 4] = *(const bf4_t*)&Ob[(size_t)(m0 + r) * ND + c * 4];
  }

  bf8_t wcur[4], wnxt[4];
  auto issue = [&](int i, bf8_t* dst) {
    const __bf16* p;
    if (i == 0)     p = Wout + (size_t)wrow * 128 + quad * 8;
    else if (i < 5) p = Wff1 + ((size_t)((i - 1) * 128 + wrow)) * 128 + quad * 8;
    else if (i < 9) p = Wff2 + (size_t)wrow * 512 + (i - 5) * 128 + quad * 8;
    else            p = Wqkv + ((size_t)((i - 9) * 128 + wrow)) * 128 + quad * 8;
#pragma unroll
    for (int kk = 0; kk < 4; kk++) dst[kk] = *(const bf8_t*)(p + kk * 32);
  };
  issue(0, wcur);
  __syncthreads();  // Xs ready

  auto do_ln = [&](const float* g_, const float* b_) {
    int r = t >> 5, c = t & 31;
    float4 v = *(const float4*)&Hs[r][c * 4];
    float s1 = v.x + v.y + v.z + v.w;
    float s2 = v.x * v.x + v.y * v.y + v.z * v.z + v.w * v.w;
#pragma unroll
    for (int m = 16; m >= 1; m >>= 1) {
      s1 += __shfl_xor(s1, m, 64);
      s2 += __shfl_xor(s2, m, 64);
    }
    float mean = s1 * (1.0f / ND);
    float var = s2 * (1.0f / ND) - mean * mean;
    float rstd = rsqrtf(var + LN_EPS);
    float4 gg = *(const float4*)&g_[c * 4];
    float4 bb = *(const float4*)&b_[c * 4];
    bf4_t p;
    p[0] = (__bf16)((v.x - mean) * rstd * gg.x + bb.x);
    p[1] = (__bf16)((v.y - mean) * rstd * gg.y + bb.y);
    p[2] = (__bf16)((v.z - mean) * rstd * gg.z + bb.z);
    p[3] = (__bf16)((v.w - mean) * rstd * gg.w + bb.w);
    *(bf4_t*)&X2[r][c * 4] = p;
  };

  f4x acc2 = {0.f, 0.f, 0.f, 0.f};
  for (int i = 0; i < T; i++) {
    if (i + 1 < T) issue(i + 1, wnxt);
    if (i == 0) {
      f4x a1 = {0.f, 0.f, 0.f, 0.f};
#pragma unroll
      for (int kk = 0; kk < 4; kk++) {
        bf8_t a = *(const bf8_t*)&Xs[l15][kk * 32 + quad * 8];
        a1 = __builtin_amdgcn_mfma_f32_16x16x32_bf16(a, wcur[kk], a1, 0, 0, 0);
      }
      int n = wrow;
      float bv = bout[n];
#pragma unroll
      for (int r = 0; r < 4; r++) {
        int m = quad * 4 + r;
        Hs[m][n] = a1[r] + bv + Hin[(size_t)(m0 + m) * ND + n];
      }
      __syncthreads();  // Hs ready
      do_ln(ln2g, ln2b);
      __syncthreads();  // X2 ready
    } else if (i < 5) {
      int c = i - 1;
      f4x a1 = {0.f, 0.f, 0.f, 0.f};
#pragma unroll
      for (int kk = 0; kk < 4; kk++) {
        bf8_t a = *(const bf8_t*)&X2[l15][kk * 32 + quad * 8];
        a1 = __builtin_amdgcn_mfma_f32_16x16x32_bf16(a, wcur[kk], a1, 0, 0, 0);
      }
      int n = wrow;
      float bv = bff1[c * 128 + n];
#pragma unroll
      for (int r = 0; r < 4; r++) {
        float v = a1[r] + bv;
        v = 0.5f * v * (1.0f + erff(v * 0.70710678118f));
        Fs[quad * 4 + r][c * 128 + n] = (__bf16)v;
      }
      if (i == 4) __syncthreads();  // Fs ready
    } else if (i < 9) {
      int j = i - 5;
#pragma unroll
      for (int kk = 0; kk < 4; kk++) {
        bf8_t a = *(const bf8_t*)&Fs[l15][j * 128 + kk * 32 + quad * 8];
        acc2 = __builtin_amdgcn_mfma_f32_16x16x32_bf16(a, wcur[kk], acc2, 0, 0, 0);
      }
      if (j == 3) {
        int n = wrow;
        float bv = bff2[n];
#pragma unroll
        for (int r = 0; r < 4; r++) {
          int m = quad * 4 + r;
          float v = acc2[r] + bv + Hs[m][n];
          Hs[m][n] = v;
          Hout[(size_t)(m0 + m) * ND + n] = v;
        }
        __syncthreads();  // Hs ready (and all ff1 X2 reads long done)
        if constexpr (!LAST) {
          do_ln(ln1g, ln1b);
          __syncthreads();  // X2' ready
        }
      }
    } else {
      int nc = i - 9;
      f4x a2 = {0.f, 0.f, 0.f, 0.f};
#pragma unroll
      for (int kk = 0; kk < 4; kk++) {
        bf8_t a = *(const bf8_t*)&X2[l15][kk * 32 + quad * 8];
        a2 = __builtin_amdgcn_mfma_f32_16x16x32_bf16(a, wcur[kk], a2, 0, 0, 0);
      }
      int n = nc * 128 + wrow;
      float bv = bqkv[n];
#pragma unroll
      for (int r = 0; r < 4; r++) {
        int m = m0 + quad * 4 + r;
        float v = a2[r] + bv;
        if (n < ND) Qb[(size_t)m * ND + n] = (__bf16)(v * QSCALE);
        else if (n < 2 * ND) Kb[(size_t)m * ND + n - ND] = (__bf16)v;
        else {
          int c2 = n - 2 * ND, hh = c2 >> 4, d0 = c2 & 15;
          int bb2 = m >> 11, nn = m & 2047;
          Vt[((size_t)((bb2 * NH + hh) * NDH + d0)) * NN + nn] = (__bf16)v;
        }
      }
    }
#pragma unroll
    for (int kk = 0; kk < 4; kk++) wcur[kk] = wnxt[kk];
  }

  if constexpr (LAST) {
    if (w < NB) {
      int rt = root_idx[w];
      int rglob = w * NN + rt;
      if (rglob >= m0 && rglob < m0 + 16) {
        int r = rglob - m0;
        float v0 = Hs[r][2 * lane], v1 = Hs[r][2 * lane + 1];
        float s1 = v0 + v1, s2 = v0 * v0 + v1 * v1;
#pragma unroll
        for (int m = 32; m >= 1; m >>= 1) {
          s1 += __shfl_xor(s1, m, 64);
          s2 += __shfl_xor(s2, m, 64);
        }
        float mean = s1 * (1.0f / ND);
        float var = s2 * (1.0f / ND) - mean * mean;
        float rstd = rsqrtf(var + LN_EPS);
        float p0 = (v0 - mean) * rstd * hg[2 * lane] + hbt[2 * lane];
        float p1 = (v1 - mean) * rstd * hg[2 * lane + 1] + hbt[2 * lane + 1];
        float part = p0 * hwp[2 * lane] + p1 * hwp[2 * lane + 1];
#pragma unroll
        for (int m = 32; m >= 1; m >>= 1) part += __shfl_xor(part, m, 64);
        if (lane == 0) outp[w] = part + hbp[0];
      }
    }
  }
}

// ---------------- MFMA flash attention v7 ----------------
__global__ __launch_bounds__(512) void attn_kernel(
    const __bf16* __restrict__ Qb, const __bf16* __restrict__ Kb,
    const __bf16* __restrict__ Vt, const unsigned int* __restrict__ adjbits,
    const unsigned int* __restrict__ maskbits, const int* __restrict__ mask,
    const float* __restrict__ sbias, int layer, __bf16* __restrict__ o) {
  int b = blockIdx.z, hh = blockIdx.y, q0 = blockIdx.x * 32;
  int wave = threadIdx.x >> 6;
  int lane = threadIdx.x & 63;
  int l31 = lane & 31, hi = lane >> 5;
  int l15 = lane & 15, quad = lane >> 4;
  float esb = __expf(sbias[layer]);
  const int bN = b * NN;
  const int kw0 = wave * 256;

  __shared__ __bf16 Pbuf[8][32][40];
  __shared__ float Ored[8][32][17];
  __shared__ float Lred[8][32];

  bf8_t Qf = *(const bf8_t*)(Qb + (size_t)(bN + q0 + l31) * ND + hh * NDH + hi * 8);

  int q = q0 + l31;
  int mq = mask[bN + q];
  const unsigned int* adjp = adjbits + (size_t)(bN + q) * (NN / 32) + (kw0 >> 5);
  const unsigned int* mbp = maskbits + (bN + kw0) / 32;
  const __bf16* kp = Kb + (size_t)(bN + kw0 + l31) * ND + hh * NDH + hi * 8;
  const __bf16* vp = Vt + (size_t)((b * NH + hh) * NDH + l15) * NN + kw0 + quad * 8;

  int dq = q - kw0;
  int tsel = dq >> 5;
  unsigned int selfw = 1u << (dq & 31);
  int sh4 = hi * 4;

  f4x Olo = {0.f, 0.f, 0.f, 0.f}, Ohi = {0.f, 0.f, 0.f, 0.f};
  float ls = 0.f;

  bf8_t Kf = *(const bf8_t*)kp;
  bf8_t Vf = *(const bf8_t*)vp;
  unsigned int aw = adjp[0];
  unsigned int mkw = mbp[0];

  for (int t = 0; t < 8; t++) {
    bf8_t Kn = Kf, Vn = Vf;
    unsigned int awn = aw, mkn = mkw;
    if (t < 7) {
      kp += 32 * ND;
      Kn = *(const bf8_t*)kp;
      Vn = *(const bf8_t*)(vp + (t + 1) * 32);
      awn = adjp[t + 1];
      mkn = mbp[t + 1];
    }
    f16x S = {0.f, 0.f, 0.f, 0.f, 0.f, 0.f, 0.f, 0.f,
              0.f, 0.f, 0.f, 0.f, 0.f, 0.f, 0.f, 0.f};
    S = __builtin_amdgcn_mfma_f32_32x32x16_bf16(Kf, Qf, S, 0, 0, 0);
    unsigned int okw = mq ? mkw : ((t == tsel) ? selfw : 0u);
    unsigned int wa = (aw & okw) >> sh4;
    unsigned int okh = okw >> sh4;
#pragma unroll
    for (int gg = 0; gg < 4; gg++) {
      bf4_t pk;
#pragma unroll
      for (int r = 0; r < 4; r++) {
        int c = gg * 8 + r;
        float e = __builtin_amdgcn_exp2f(S[gg * 4 + r]);
        float wgt = ((wa >> c) & 1) ? esb : (((okh >> c) & 1) ? 1.0f : 0.0f);
        float p = e * wgt;
        ls += p;
        pk[r] = (__bf16)p;
      }
      *(bf4_t*)&Pbuf[wave][l31][sh4 + gg * 8] = pk;
    }
    asm volatile("s_waitcnt lgkmcnt(0)" ::: "memory");
    bf8_t Plo = *(const bf8_t*)&Pbuf[wave][l15][quad * 8];
    bf8_t Phi = *(const bf8_t*)&Pbuf[wave][16 + l15][quad * 8];
    Olo = __builtin_amdgcn_mfma_f32_16x16x32_bf16(Plo, Vf, Olo, 0, 0, 0);
    Ohi = __builtin_amdgcn_mfma_f32_16x16x32_bf16(Phi, Vf, Ohi, 0, 0, 0);
    Kf = Kn; Vf = Vn; aw = awn; mkw = mkn;
  }

  ls += __shfl_xor(ls, 32, 64);
  if (hi == 0) Lred[wave][l31] = ls;
#pragma unroll
  for (int r = 0; r < 4; r++) {
    Ored[wave][quad * 4 + r][l15] = Olo[r];
    Ored[wave][16 + quad * 4 + r][l15] = Ohi[r];
  }
  __syncthreads();
  int row = threadIdx.x >> 4, col = threadIdx.x & 15;
  float s = 0.f, L = 0.f;
#pragma unroll
  for (int p = 0; p < 8; p++) {
    s += Ored[p][row][col];
    L += Lred[p][row];
  }
  o[(size_t)(bN + q0 + row) * ND + hh * NDH + col] = (__bf16)(s / L);
}

extern "C" void kernel_launch(void* const* d_in, const int* in_sizes, int n_in,
                              void* d_out, int out_size, void* d_ws, size_t ws_size,
                              hipStream_t stream) {
  const float* atom_embed = (const float*)d_in[0];
  const float* cons_embed = (const float*)d_in[1];
  const float* in_w  = (const float*)d_in[2];
  const float* in_b  = (const float*)d_in[3];
  const float* qkv_w = (const float*)d_in[4];
  const float* qkv_b = (const float*)d_in[5];
  const float* out_w = (const float*)d_in[6];
  const float* out_b = (const float*)d_in[7];
  const float* ln1_g = (const float*)d_in[8];
  const float* ln1_b = (const float*)d_in[9];
  const float* ln2_g = (const float*)d_in[10];
  const float* ln2_b = (const float*)d_in[11];
  const float* ff1_w = (const float*)d_in[12];
  const float* ff1_b = (const float*)d_in[13];
  const float* ff2_w = (const float*)d_in[14];
  const float* ff2_b = (const float*)d_in[15];
  const float* sbias = (const float*)d_in[16];
  const float* hg    = (const float*)d_in[17];
  const float* hbt   = (const float*)d_in[18];
  const float* hw    = (const float*)d_in[19];
  const float* hb    = (const float*)d_in[20];
  const float* adj   = (const float*)d_in[21];
  const int* is_atom = (const int*)d_in[22];
  const int* atom_id = (const int*)d_in[23];
  const int* mask    = (const int*)d_in[24];
  const int* root_idx= (const int*)d_in[25];
  float* out = (float*)d_out;

  const int MR = NB * NN;  // 4096 rows
  float* hA = (float*)d_ws;
  float* hB = hA + MR * ND;
  __bf16* Qb   = (__bf16*)(hB + MR * ND);
  __bf16* Kb   = Qb + MR * ND;
  __bf16* Vt   = Kb + MR * ND;
  __bf16* wbin = Vt + MR * ND;
  __bf16* wbqkv= wbin + ND * ND;
  __bf16* wbout= wbqkv + NL * 384 * ND;
  __bf16* wbff1= wbout + NL * ND * ND;
  __bf16* wbff2= wbff1 + NL * 512 * ND;
  unsigned int* adjb = (unsigned int*)(wbff2 + NL * ND * 512);
  unsigned int* mskb = adjb + NB * NN * NN / 32;
  __bf16* ob = (__bf16*)(mskb + 128);

  CastArgs ca;
  ca.s[0] = in_w;  ca.d[0] = wbin;  ca.startblk[0] = 0;
  ca.s[1] = qkv_w; ca.d[1] = wbqkv; ca.startblk[1] = 16;
  ca.s[2] = out_w; ca.d[2] = wbout; ca.startblk[2] = 160;
  ca.s[3] = ff1_w; ca.d[3] = wbff1; ca.startblk[3] = 208;
  ca.s[4] = ff2_w; ca.d[4] = wbff2; ca.startblk[4] = 400;
  prep_kernel<<<8800, 256, 0, stream>>>(ca, adj, (unsigned long long*)adjb,
                                        mask, (unsigned long long*)mskb);

  fused0_kernel<<<dim3(MR / 16), 512, 0, stream>>>(
      atom_embed, cons_embed, is_atom, atom_id,
      wbin, in_b, hA, ln1_g, ln1_b, wbqkv, qkv_b, Qb, Kb, Vt);

  const float* hin[3]  = {hA, hB, hA};
  float* hout[3]       = {hB, hA, hB};
  for (int i = 0; i < NL; i++) {
    attn_kernel<<<dim3(NN / 32, NH, NB), 512, 0, stream>>>(
        Qb, Kb, Vt, adjb, mskb, mask, sbias, i, ob);
    if (i < NL - 1) {
      layer_kernel<0><<<dim3(MR / 16), 512, 0, stream>>>(
          ob, wbout + (size_t)i * ND * ND, out_b + i * ND, hin[i], hout[i],
          ln2_g + i * ND, ln2_b + i * ND,
          wbff1 + (size_t)i * 512 * ND, ff1_b + i * 512,
          wbff2 + (size_t)i * ND * 512, ff2_b + i * ND,
          ln1_g + (i + 1) * ND, ln1_b + (i + 1) * ND,
          wbqkv + (size_t)(i + 1) * 384 * ND, qkv_b + (i + 1) * 384,
          Qb, Kb, Vt,
          nullptr, nullptr, nullptr, nullptr, nullptr, nullptr);
    } else {
      layer_kernel<1><<<dim3(MR / 16), 512, 0, stream>>>(
          ob, wbout + (size_t)i * ND * ND, out_b + i * ND, hin[i], hout[i],
          ln2_g + i * ND, ln2_b + i * ND,
          wbff1 + (size_t)i * 512 * ND, ff1_b + i * 512,
          wbff2 + (size_t)i * ND * 512, ff2_b + i * ND,
          nullptr, nullptr, nullptr, nullptr,
          nullptr, nullptr, nullptr,
          root_idx, hg, hbt, hw, hb, out);
    }
  }
}

// Round 2
// 258.666 us; speedup vs baseline: 1.0047x; 1.0035x over previous
//
#include <hip/hip_runtime.h>
#include <cmath>

#define NB 2
#define NN 2048
#define ND 128
#define NH 8
#define NL 3
#define NV 32
#define NDH 16
#define LN_EPS 1e-5f
/* ATT_SCALE(0.25) * log2(e), folded into Q at qkv-pack time so the attention
   inner loop is a raw exp2 per score. */
#define QSCALE 0.36067376022224085f

typedef __bf16 bf8_t __attribute__((ext_vector_type(8)));
typedef __bf16 bf4_t __attribute__((ext_vector_type(4)));
typedef float f4x __attribute__((ext_vector_type(4)));
typedef float f16x __attribute__((ext_vector_type(16)));

// ---------------- one prep kernel: weight casts + adjacency/mask bitpack ----
struct CastArgs {
  const float* s[5];
  __bf16* d[5];
  int startblk[5];
};
// blocks [0,592): casts; [592, 592+8192): adj bitpack; [8784, 8800): mask bitpack
__global__ __launch_bounds__(256) void prep_kernel(
    CastArgs a, const float* __restrict__ adj, unsigned long long* __restrict__ abits,
    const int* __restrict__ mask, unsigned long long* __restrict__ mbits) {
  int blk = blockIdx.x;
  int lane = threadIdx.x & 63;
  if (blk < 592) {
    int seg = 0;
#pragma unroll
    for (int i = 1; i < 5; i++) seg += (blk >= a.startblk[i]) ? 1 : 0;
    int i4 = (blk - a.startblk[seg]) * 256 + threadIdx.x;
    float4 v = ((const float4*)a.s[seg])[i4];
    bf4_t p = {(__bf16)v.x, (__bf16)v.y, (__bf16)v.z, (__bf16)v.w};
    ((bf4_t*)a.d[seg])[i4] = p;
  } else if (blk < 592 + 8192) {
    int g = ((blk - 592) * 4 + (threadIdx.x >> 6)) * 4;
    const float* p = adj + (size_t)g * 64 + lane;
    unsigned long long w0 = __ballot(p[0] != 0.0f);
    unsigned long long w1 = __ballot(p[64] != 0.0f);
    unsigned long long w2 = __ballot(p[128] != 0.0f);
    unsigned long long w3 = __ballot(p[192] != 0.0f);
    if (lane == 0) {
      abits[g] = w0; abits[g + 1] = w1; abits[g + 2] = w2; abits[g + 3] = w3;
    }
  } else {
    int g = (blk - 8784) * 4 + (threadIdx.x >> 6);
    int v = mask[g * 64 + lane];
    unsigned long long bal = __ballot(v != 0);
    if (lane == 0) mbits[g] = bal;
  }
}

// ---------------- fused0: embed + in-proj + LN1[0] + qkv[0] ----
__global__ __launch_bounds__(512) void fused0_kernel(
    const float* __restrict__ atom_embed, const float* __restrict__ cons_embed,
    const int* __restrict__ is_atom, const int* __restrict__ atom_id,
    const __bf16* __restrict__ W1, const float* __restrict__ b1,
    float* __restrict__ Hout,
    const float* __restrict__ lng, const float* __restrict__ lnb,
    const __bf16* __restrict__ W2, const float* __restrict__ b2,
    __bf16* __restrict__ Qb, __bf16* __restrict__ Kb, __bf16* __restrict__ Vt) {
  __shared__ __bf16 Xs[16][136];
  __shared__ float Hs[16][132];
  __shared__ __bf16 X2[16][136];
  int m0 = blockIdx.x * 16;
  int t = threadIdx.x;
  int lane = t & 63, w = t >> 6;
  int l15 = lane & 15, quad = lane >> 4;
  int wrow = w * 16 + l15;

  {
    int r = t >> 5, c = t & 31;
    int row = m0 + r;
    int id = atom_id[row];
    id = id < 0 ? 0 : (id > NV - 1 ? NV - 1 : id);
    const float* src = is_atom[row] ? (atom_embed + (size_t)id * ND) : cons_embed;
    float4 v = *(const float4*)&src[c * 4];
    bf4_t p = {(__bf16)v.x, (__bf16)v.y, (__bf16)v.z, (__bf16)v.w};
    *(bf4_t*)&Xs[r][c * 4] = p;
  }

  bf8_t wcur[4], wnxt[4];
  auto issue = [&](int i, bf8_t* dst) {
    const __bf16* base = (i == 0) ? W1 : (W2 + (size_t)(i - 1) * 128 * 128);
    const __bf16* p = base + (size_t)wrow * 128 + quad * 8;
#pragma unroll
    for (int kk = 0; kk < 4; kk++) dst[kk] = *(const bf8_t*)(p + kk * 32);
  };
  issue(0, wcur);
  __syncthreads();  // Xs ready

  for (int i = 0; i < 4; i++) {
    if (i + 1 < 4) issue(i + 1, wnxt);
    if (i == 0) {
      f4x a1 = {0.f, 0.f, 0.f, 0.f};
#pragma unroll
      for (int kk = 0; kk < 4; kk++) {
        bf8_t a = *(const bf8_t*)&Xs[l15][kk * 32 + quad * 8];
        a1 = __builtin_amdgcn_mfma_f32_16x16x32_bf16(a, wcur[kk], a1, 0, 0, 0);
      }
      int n = wrow;
      float bv = b1[n];
#pragma unroll
      for (int r = 0; r < 4; r++) {
        int m = quad * 4 + r;
        float v = a1[r] + bv;
        Hout[(size_t)(m0 + m) * ND + n] = v;
        Hs[m][n] = v;
      }
      __syncthreads();  // Hs ready
      {
        int r = t >> 5, c = t & 31;
        float4 v = *(const float4*)&Hs[r][c * 4];
        float s1 = v.x + v.y + v.z + v.w;
        float s2 = v.x * v.x + v.y * v.y + v.z * v.z + v.w * v.w;
#pragma unroll
        for (int m = 16; m >= 1; m >>= 1) {
          s1 += __shfl_xor(s1, m, 64);
          s2 += __shfl_xor(s2, m, 64);
        }
        float mean = s1 * (1.0f / ND);
        float var = s2 * (1.0f / ND) - mean * mean;
        float rstd = rsqrtf(var + LN_EPS);
        float4 gg = *(const float4*)&lng[c * 4];
        float4 bb = *(const float4*)&lnb[c * 4];
        bf4_t p;
        p[0] = (__bf16)((v.x - mean) * rstd * gg.x + bb.x);
        p[1] = (__bf16)((v.y - mean) * rstd * gg.y + bb.y);
        p[2] = (__bf16)((v.z - mean) * rstd * gg.z + bb.z);
        p[3] = (__bf16)((v.w - mean) * rstd * gg.w + bb.w);
        *(bf4_t*)&X2[r][c * 4] = p;
      }
      __syncthreads();  // X2 ready
    } else {
      int nc = i - 1;
      f4x a2 = {0.f, 0.f, 0.f, 0.f};
#pragma unroll
      for (int kk = 0; kk < 4; kk++) {
        bf8_t a = *(const bf8_t*)&X2[l15][kk * 32 + quad * 8];
        a2 = __builtin_amdgcn_mfma_f32_16x16x32_bf16(a, wcur[kk], a2, 0, 0, 0);
      }
      int n = nc * 128 + wrow;
      float bv = b2[n];
#pragma unroll
      for (int r = 0; r < 4; r++) {
        int m = m0 + quad * 4 + r;
        float v = a2[r] + bv;
        if (n < ND) Qb[(size_t)m * ND + n] = (__bf16)(v * QSCALE);
        else if (n < 2 * ND) Kb[(size_t)m * ND + n - ND] = (__bf16)v;
        else {
          int c2 = n - 2 * ND, hh = c2 >> 4, d0 = c2 & 15;
          int bb2 = m >> 11, nn = m & 2047;
          Vt[((size_t)((bb2 * NH + hh) * NDH + d0)) * NN + nn] = (__bf16)v;
        }
      }
    }
#pragma unroll
    for (int kk = 0; kk < 4; kk++) wcur[kk] = wnxt[kk];
  }
}

// ---------------- per-layer mega kernel ----------------
template <int LAST>
__global__ __launch_bounds__(512) void layer_kernel(
    const __bf16* __restrict__ Ob,
    const __bf16* __restrict__ Wout, const float* __restrict__ bout,
    const float* __restrict__ Hin, float* __restrict__ Hout,
    const float* __restrict__ ln2g, const float* __restrict__ ln2b,
    const __bf16* __restrict__ Wff1, const float* __restrict__ bff1,
    const __bf16* __restrict__ Wff2, const float* __restrict__ bff2,
    const float* __restrict__ ln1g, const float* __restrict__ ln1b,
    const __bf16* __restrict__ Wqkv, const float* __restrict__ bqkv,
    __bf16* __restrict__ Qb, __bf16* __restrict__ Kb, __bf16* __restrict__ Vt,
    const int* __restrict__ root_idx, const float* __restrict__ hg,
    const float* __restrict__ hbt, const float* __restrict__ hwp,
    const float* __restrict__ hbp, float* __restrict__ outp) {
  __shared__ __bf16 Xs[16][136];
  __shared__ float Hs[16][132];
  __shared__ __bf16 X2[16][136];
  __shared__ __bf16 Fs[16][520];
  int m0 = blockIdx.x * 16;
  int t = threadIdx.x;
  int lane = t & 63, w = t >> 6;
  int l15 = lane & 15, quad = lane >> 4;
  int wrow = w * 16 + l15;
  const int T = LAST ? 9 : 12;

  {
    int r = t >> 5, c = t & 31;
    *(bf4_t*)&Xs[r][c * 4] = *(const bf4_t*)&Ob[(size_t)(m0 + r) * ND + c * 4];
  }

  bf8_t wcur[4], wnxt[4];
  auto issue = [&](int i, bf8_t* dst) {
    const __bf16* p;
    if (i == 0)     p = Wout + (size_t)wrow * 128 + quad * 8;
    else if (i < 5) p = Wff1 + ((size_t)((i - 1) * 128 + wrow)) * 128 + quad * 8;
    else if (i < 9) p = Wff2 + (size_t)wrow * 512 + (i - 5) * 128 + quad * 8;
    else            p = Wqkv + ((size_t)((i - 9) * 128 + wrow)) * 128 + quad * 8;
#pragma unroll
    for (int kk = 0; kk < 4; kk++) dst[kk] = *(const bf8_t*)(p + kk * 32);
  };
  issue(0, wcur);
  __syncthreads();  // Xs ready

  auto do_ln = [&](const float* g_, const float* b_) {
    int r = t >> 5, c = t & 31;
    float4 v = *(const float4*)&Hs[r][c * 4];
    float s1 = v.x + v.y + v.z + v.w;
    float s2 = v.x * v.x + v.y * v.y + v.z * v.z + v.w * v.w;
#pragma unroll
    for (int m = 16; m >= 1; m >>= 1) {
      s1 += __shfl_xor(s1, m, 64);
      s2 += __shfl_xor(s2, m, 64);
    }
    float mean = s1 * (1.0f / ND);
    float var = s2 * (1.0f / ND) - mean * mean;
    float rstd = rsqrtf(var + LN_EPS);
    float4 gg = *(const float4*)&g_[c * 4];
    float4 bb = *(const float4*)&b_[c * 4];
    bf4_t p;
    p[0] = (__bf16)((v.x - mean) * rstd * gg.x + bb.x);
    p[1] = (__bf16)((v.y - mean) * rstd * gg.y + bb.y);
    p[2] = (__bf16)((v.z - mean) * rstd * gg.z + bb.z);
    p[3] = (__bf16)((v.w - mean) * rstd * gg.w + bb.w);
    *(bf4_t*)&X2[r][c * 4] = p;
  };

  f4x acc2 = {0.f, 0.f, 0.f, 0.f};
  for (int i = 0; i < T; i++) {
    if (i + 1 < T) issue(i + 1, wnxt);
    if (i == 0) {
      f4x a1 = {0.f, 0.f, 0.f, 0.f};
#pragma unroll
      for (int kk = 0; kk < 4; kk++) {
        bf8_t a = *(const bf8_t*)&Xs[l15][kk * 32 + quad * 8];
        a1 = __builtin_amdgcn_mfma_f32_16x16x32_bf16(a, wcur[kk], a1, 0, 0, 0);
      }
      int n = wrow;
      float bv = bout[n];
#pragma unroll
      for (int r = 0; r < 4; r++) {
        int m = quad * 4 + r;
        Hs[m][n] = a1[r] + bv + Hin[(size_t)(m0 + m) * ND + n];
      }
      __syncthreads();  // Hs ready
      do_ln(ln2g, ln2b);
      __syncthreads();  // X2 ready
    } else if (i < 5) {
      int c = i - 1;
      f4x a1 = {0.f, 0.f, 0.f, 0.f};
#pragma unroll
      for (int kk = 0; kk < 4; kk++) {
        bf8_t a = *(const bf8_t*)&X2[l15][kk * 32 + quad * 8];
        a1 = __builtin_amdgcn_mfma_f32_16x16x32_bf16(a, wcur[kk], a1, 0, 0, 0);
      }
      int n = wrow;
      float bv = bff1[c * 128 + n];
#pragma unroll
      for (int r = 0; r < 4; r++) {
        float v = a1[r] + bv;
        v = 0.5f * v * (1.0f + erff(v * 0.70710678118f));
        Fs[quad * 4 + r][c * 128 + n] = (__bf16)v;
      }
      if (i == 4) __syncthreads();  // Fs ready
    } else if (i < 9) {
      int j = i - 5;
#pragma unroll
      for (int kk = 0; kk < 4; kk++) {
        bf8_t a = *(const bf8_t*)&Fs[l15][j * 128 + kk * 32 + quad * 8];
        acc2 = __builtin_amdgcn_mfma_f32_16x16x32_bf16(a, wcur[kk], acc2, 0, 0, 0);
      }
      if (j == 3) {
        int n = wrow;
        float bv = bff2[n];
#pragma unroll
        for (int r = 0; r < 4; r++) {
          int m = quad * 4 + r;
          float v = acc2[r] + bv + Hs[m][n];
          Hs[m][n] = v;
          Hout[(size_t)(m0 + m) * ND + n] = v;
        }
        __syncthreads();  // Hs ready
        if constexpr (!LAST) {
          do_ln(ln1g, ln1b);
          __syncthreads();  // X2' ready
        }
      }
    } else {
      int nc = i - 9;
      f4x a2 = {0.f, 0.f, 0.f, 0.f};
#pragma unroll
      for (int kk = 0; kk < 4; kk++) {
        bf8_t a = *(const bf8_t*)&X2[l15][kk * 32 + quad * 8];
        a2 = __builtin_amdgcn_mfma_f32_16x16x32_bf16(a, wcur[kk], a2, 0, 0, 0);
      }
      int n = nc * 128 + wrow;
      float bv = bqkv[n];
#pragma unroll
      for (int r = 0; r < 4; r++) {
        int m = m0 + quad * 4 + r;
        float v = a2[r] + bv;
        if (n < ND) Qb[(size_t)m * ND + n] = (__bf16)(v * QSCALE);
        else if (n < 2 * ND) Kb[(size_t)m * ND + n - ND] = (__bf16)v;
        else {
          int c2 = n - 2 * ND, hh = c2 >> 4, d0 = c2 & 15;
          int bb2 = m >> 11, nn = m & 2047;
          Vt[((size_t)((bb2 * NH + hh) * NDH + d0)) * NN + nn] = (__bf16)v;
        }
      }
    }
#pragma unroll
    for (int kk = 0; kk < 4; kk++) wcur[kk] = wnxt[kk];
  }

  if constexpr (LAST) {
    if (w < NB) {
      int rt = root_idx[w];
      int rglob = w * NN + rt;
      if (rglob >= m0 && rglob < m0 + 16) {
        int r = rglob - m0;
        float v0 = Hs[r][2 * lane], v1 = Hs[r][2 * lane + 1];
        float s1 = v0 + v1, s2 = v0 * v0 + v1 * v1;
#pragma unroll
        for (int m = 32; m >= 1; m >>= 1) {
          s1 += __shfl_xor(s1, m, 64);
          s2 += __shfl_xor(s2, m, 64);
        }
        float mean = s1 * (1.0f / ND);
        float var = s2 * (1.0f / ND) - mean * mean;
        float rstd = rsqrtf(var + LN_EPS);
        float p0 = (v0 - mean) * rstd * hg[2 * lane] + hbt[2 * lane];
        float p1 = (v1 - mean) * rstd * hg[2 * lane + 1] + hbt[2 * lane + 1];
        float part = p0 * hwp[2 * lane] + p1 * hwp[2 * lane + 1];
#pragma unroll
        for (int m = 32; m >= 1; m >>= 1) part += __shfl_xor(part, m, 64);
        if (lane == 0) outp[w] = part + hbp[0];
      }
    }
  }
}

// ---------------- MFMA flash attention v8 ----------------
// Pair-mask (mq&mk) folded into S via a second rank-2 MFMA:
//   S += A2.B2 with A2[k] = [mk, 1, 0...], B2[q] = [128*mq, -128, 0...]
//   => exact 0.0 for valid pairs, -128 for blocked (exp2 -> ~2^-128 ~ 0).
// Adjacency (0.2% + diagonal) applied as a sparse LDS fixup over the set
// bits of (aw & mkw) instead of per-score cndmask chains. Invalid-q rows
// (softmax over self only => weight == 1 exactly) just write 1.0 at the
// self column. Inner loop per score: exp2 + ls-add + cvt (~2.5 VALU slots
// vs ~9 before).
__global__ __launch_bounds__(512) void attn_kernel(
    const __bf16* __restrict__ Qb, const __bf16* __restrict__ Kb,
    const __bf16* __restrict__ Vt, const unsigned int* __restrict__ adjbits,
    const unsigned int* __restrict__ maskbits, const int* __restrict__ mask,
    const float* __restrict__ sbias, int layer, __bf16* __restrict__ o) {
  int b = blockIdx.z, hh = blockIdx.y, q0 = blockIdx.x * 32;
  int wave = threadIdx.x >> 6;
  int lane = threadIdx.x & 63;
  int l31 = lane & 31, hi = lane >> 5;
  int l15 = lane & 15, quad = lane >> 4;
  float esb = __expf(sbias[layer]);
  float esbm1 = esb - 1.0f;
  const int bN = b * NN;
  const int kw0 = wave * 256;

  __shared__ __bf16 Pbuf[8][32][40];
  __shared__ float Ored[8][32][17];
  __shared__ float Lred[8][32];

  bf8_t Qf = *(const bf8_t*)(Qb + (size_t)(bN + q0 + l31) * ND + hh * NDH + hi * 8);

  int q = q0 + l31;
  int mq = mask[bN + q];
  const unsigned int* adjp = adjbits + (size_t)(bN + q) * (NN / 32) + (kw0 >> 5);
  const unsigned int* mbp = maskbits + (bN + kw0) / 32;
  const __bf16* kp = Kb + (size_t)(bN + kw0 + l31) * ND + hh * NDH + hi * 8;
  const __bf16* vp = Vt + (size_t)((b * NH + hh) * NDH + l15) * NN + kw0 + quad * 8;

  int dq = q - kw0;
  int tsel = dq >> 5;
  int sh4 = hi * 4;

  // Q-side mask operand: [128*mq, -128, 0...] on hi==0 lanes, zeros on hi==1.
  union { bf8_t v; unsigned int u[4]; } Qmu;
  {
    unsigned int qw0 = (mq ? 0x4300u : 0u) | (0xC300u << 16);
    Qmu.u[0] = hi ? 0u : qw0;
    Qmu.u[1] = 0u; Qmu.u[2] = 0u; Qmu.u[3] = 0u;
  }

  f4x Olo = {0.f, 0.f, 0.f, 0.f}, Ohi = {0.f, 0.f, 0.f, 0.f};
  float ls = 0.f;

  bf8_t Kf = *(const bf8_t*)kp;
  bf8_t Vf = *(const bf8_t*)vp;
  unsigned int aw = adjp[0];
  unsigned int mkw = mbp[0];

  for (int t = 0; t < 8; t++) {
    bf8_t Kn = Kf, Vn = Vf;
    unsigned int awn = aw, mkn = mkw;
    if (t < 7) {
      kp += 32 * ND;
      Kn = *(const bf8_t*)kp;
      Vn = *(const bf8_t*)(vp + (t + 1) * 32);
      awn = adjp[t + 1];
      mkn = mbp[t + 1];
    }
    // K-side mask operand for this tile: [mk, 1, 0...] per key row.
    union { bf8_t v; unsigned int u[4]; } Mfu;
    {
      unsigned int mw0 = (((mkw >> l31) & 1u) ? 0x3F80u : 0u) | (0x3F80u << 16);
      Mfu.u[0] = hi ? 0u : mw0;
      Mfu.u[1] = 0u; Mfu.u[2] = 0u; Mfu.u[3] = 0u;
    }
    f16x S = {0.f, 0.f, 0.f, 0.f, 0.f, 0.f, 0.f, 0.f,
              0.f, 0.f, 0.f, 0.f, 0.f, 0.f, 0.f, 0.f};
    S = __builtin_amdgcn_mfma_f32_32x32x16_bf16(Kf, Qf, S, 0, 0, 0);
    S = __builtin_amdgcn_mfma_f32_32x32x16_bf16(Mfu.v, Qmu.v, S, 0, 0, 0);
#pragma unroll
    for (int gg = 0; gg < 4; gg++) {
      bf4_t pk;
#pragma unroll
      for (int r = 0; r < 4; r++) {
        float e = __builtin_amdgcn_exp2f(S[gg * 4 + r]);
        ls += e;
        pk[r] = (__bf16)e;
      }
      *(bf4_t*)&Pbuf[wave][l31][sh4 + gg * 8] = pk;
    }
    asm volatile("s_waitcnt lgkmcnt(0)" ::: "memory");
    // Invalid-q rows: softmax over the self element alone => weight 1.
    if (!mq && t == tsel && hi == 0) {
      Pbuf[wave][l31][dq & 31] = (__bf16)1.0f;
      ls += 1.0f;
    }
    // Sparse adjacency fixup: each lane fixes only columns it wrote.
    unsigned int fb = ((aw & mkw) >> sh4) & 0x0f0f0f0fu;
    while (fb) {
      int c = __builtin_ctz(fb);
      fb &= fb - 1;
      __bf16* ap = &Pbuf[wave][l31][sh4 + c];
      float old = (float)*ap;
      *ap = (__bf16)(old * esb);
      ls += old * esbm1;
    }
    asm volatile("s_waitcnt lgkmcnt(0)" ::: "memory");
    bf8_t Plo = *(const bf8_t*)&Pbuf[wave][l15][quad * 8];
    bf8_t Phi = *(const bf8_t*)&Pbuf[wave][16 + l15][quad * 8];
    Olo = __builtin_amdgcn_mfma_f32_16x16x32_bf16(Plo, Vf, Olo, 0, 0, 0);
    Ohi = __builtin_amdgcn_mfma_f32_16x16x32_bf16(Phi, Vf, Ohi, 0, 0, 0);
    Kf = Kn; Vf = Vn; aw = awn; mkw = mkn;
  }

  ls += __shfl_xor(ls, 32, 64);
  if (hi == 0) Lred[wave][l31] = ls;
#pragma unroll
  for (int r = 0; r < 4; r++) {
    Ored[wave][quad * 4 + r][l15] = Olo[r];
    Ored[wave][16 + quad * 4 + r][l15] = Ohi[r];
  }
  __syncthreads();
  int row = threadIdx.x >> 4, col = threadIdx.x & 15;
  float s = 0.f, L = 0.f;
#pragma unroll
  for (int p = 0; p < 8; p++) {
    s += Ored[p][row][col];
    L += Lred[p][row];
  }
  o[(size_t)(bN + q0 + row) * ND + hh * NDH + col] = (__bf16)(s / L);
}

extern "C" void kernel_launch(void* const* d_in, const int* in_sizes, int n_in,
                              void* d_out, int out_size, void* d_ws, size_t ws_size,
                              hipStream_t stream) {
  const float* atom_embed = (const float*)d_in[0];
  const float* cons_embed = (const float*)d_in[1];
  const float* in_w  = (const float*)d_in[2];
  const float* in_b  = (const float*)d_in[3];
  const float* qkv_w = (const float*)d_in[4];
  const float* qkv_b = (const float*)d_in[5];
  const float* out_w = (const float*)d_in[6];
  const float* out_b = (const float*)d_in[7];
  const float* ln1_g = (const float*)d_in[8];
  const float* ln1_b = (const float*)d_in[9];
  const float* ln2_g = (const float*)d_in[10];
  const float* ln2_b = (const float*)d_in[11];
  const float* ff1_w = (const float*)d_in[12];
  const float* ff1_b = (const float*)d_in[13];
  const float* ff2_w = (const float*)d_in[14];
  const float* ff2_b = (const float*)d_in[15];
  const float* sbias = (const float*)d_in[16];
  const float* hg    = (const float*)d_in[17];
  const float* hbt   = (const float*)d_in[18];
  const float* hw    = (const float*)d_in[19];
  const float* hb    = (const float*)d_in[20];
  const float* adj   = (const float*)d_in[21];
  const int* is_atom = (const int*)d_in[22];
  const int* atom_id = (const int*)d_in[23];
  const int* mask    = (const int*)d_in[24];
  const int* root_idx= (const int*)d_in[25];
  float* out = (float*)d_out;

  const int MR = NB * NN;  // 4096 rows
  float* hA = (float*)d_ws;
  float* hB = hA + MR * ND;
  __bf16* Qb   = (__bf16*)(hB + MR * ND);
  __bf16* Kb   = Qb + MR * ND;
  __bf16* Vt   = Kb + MR * ND;
  __bf16* wbin = Vt + MR * ND;
  __bf16* wbqkv= wbin + ND * ND;
  __bf16* wbout= wbqkv + NL * 384 * ND;
  __bf16* wbff1= wbout + NL * ND * ND;
  __bf16* wbff2= wbff1 + NL * 512 * ND;
  unsigned int* adjb = (unsigned int*)(wbff2 + NL * ND * 512);
  unsigned int* mskb = adjb + NB * NN * NN / 32;
  __bf16* ob = (__bf16*)(mskb + 128);

  CastArgs ca;
  ca.s[0] = in_w;  ca.d[0] = wbin;  ca.startblk[0] = 0;
  ca.s[1] = qkv_w; ca.d[1] = wbqkv; ca.startblk[1] = 16;
  ca.s[2] = out_w; ca.d[2] = wbout; ca.startblk[2] = 160;
  ca.s[3] = ff1_w; ca.d[3] = wbff1; ca.startblk[3] = 208;
  ca.s[4] = ff2_w; ca.d[4] = wbff2; ca.startblk[4] = 400;
  prep_kernel<<<8800, 256, 0, stream>>>(ca, adj, (unsigned long long*)adjb,
                                        mask, (unsigned long long*)mskb);

  fused0_kernel<<<dim3(MR / 16), 512, 0, stream>>>(
      atom_embed, cons_embed, is_atom, atom_id,
      wbin, in_b, hA, ln1_g, ln1_b, wbqkv, qkv_b, Qb, Kb, Vt);

  const float* hin[3]  = {hA, hB, hA};
  float* hout[3]       = {hB, hA, hB};
  for (int i = 0; i < NL; i++) {
    attn_kernel<<<dim3(NN / 32, NH, NB), 512, 0, stream>>>(
        Qb, Kb, Vt, adjb, mskb, mask, sbias, i, ob);
    if (i < NL - 1) {
      layer_kernel<0><<<dim3(MR / 16), 512, 0, stream>>>(
          ob, wbout + (size_t)i * ND * ND, out_b + i * ND, hin[i], hout[i],
          ln2_g + i * ND, ln2_b + i * ND,
          wbff1 + (size_t)i * 512 * ND, ff1_b + i * 512,
          wbff2 + (size_t)i * ND * 512, ff2_b + i * ND,
          ln1_g + (i + 1) * ND, ln1_b + (i + 1) * ND,
          wbqkv + (size_t)(i + 1) * 384 * ND, qkv_b + (i + 1) * 384,
          Qb, Kb, Vt,
          nullptr, nullptr, nullptr, nullptr, nullptr, nullptr);
    } else {
      layer_kernel<1><<<dim3(MR / 16), 512, 0, stream>>>(
          ob, wbout + (size_t)i * ND * ND, out_b + i * ND, hin[i], hout[i],
          ln2_g + i * ND, ln2_b + i * ND,
          wbff1 + (size_t)i * 512 * ND, ff1_b + i * 512,
          wbff2 + (size_t)i * ND * 512, ff2_b + i * ND,
          nullptr, nullptr, nullptr, nullptr,
          nullptr, nullptr, nullptr,
          root_idx, hg, hbt, hw, hb, out);
    }
  }
}